// Round 2
// baseline (413.679 us; speedup 1.0000x reference)
//
#include <hip/hip_runtime.h>
#include <math.h>

#define NROWS 8192
#define DDIM  4096
#define NEXP  64
#define KSPLIT 2
#define KHALF (DDIM/KSPLIT)   // 2048
#define BROWS 64
#define BK    128
#define NKT   (KHALF/BK)      // 16

// Kernel 0: transpose W (E x D) -> WT (D x E) so per-k expert rows are contiguous.
__global__ __launch_bounds__(256) void transpose_w_kernel(
    const float* __restrict__ w, float* __restrict__ wt)
{
    __shared__ float tile[64][65];
    const int k0 = blockIdx.x * 64;
    const int t  = threadIdx.x;
    {
        const int e  = t >> 2;            // 0..63
        const int kc = (t & 3) * 16;      // 0,16,32,48
        const float* p = w + (size_t)e * DDIM + k0 + kc;
#pragma unroll
        for (int u = 0; u < 4; u++) {
            float4 v = *(const float4*)(p + 4 * u);
            *(float4*)&tile[e][kc + 4 * u] = v;
        }
    }
    __syncthreads();
    {
        const int kr = t >> 2;            // 0..63
        const int ec = (t & 3) * 16;      // 0,16,32,48
        float* q = wt + (size_t)(k0 + kr) * NEXP + ec;
#pragma unroll
        for (int u = 0; u < 16; u++) q[u] = tile[ec + u][kr];
    }
}

// Kernel 1: partial logits, split-K=2. part[kh][row][e].
// Tile 64 rows x 64 experts. 256 threads. Thread = 1 row x 16 experts;
// wave wv covers experts [16*wv, 16*wv+16) -> W loads are wave-uniform (scalar path).
__global__ __launch_bounds__(256) void gemm_partial_kernel(
    const float* __restrict__ x, const float* __restrict__ wt,
    float* __restrict__ part)
{
    __shared__ float xs[BROWS][BK + 1];   // stride 129 == 1 mod 32: conflict-free
    const int tid = threadIdx.x;
    const int row = tid & 63;
    const int wv  = __builtin_amdgcn_readfirstlane(tid >> 6);  // wave id 0..3, uniform
    const int r0  = blockIdx.x * BROWS;
    const int kh  = blockIdx.y;

    // staging: 64x128 floats / 256 thr = 8 float4 per thread
    const int srow = tid >> 2;            // 0..63
    const int sc0  = (tid & 3) * 4;       // lane-cluster base; +16*u per float4
    const float* xp = x + (size_t)(r0 + srow) * DDIM + (size_t)kh * KHALF + sc0;
    const float* wp = wt + (size_t)kh * KHALF * NEXP + wv * 16;

    float acc[16];
#pragma unroll
    for (int j = 0; j < 16; j++) acc[j] = 0.f;

    for (int kt = 0; kt < NKT; kt++) {
        float4 st[8];
        const float* xpt = xp + kt * BK;
#pragma unroll
        for (int u = 0; u < 8; u++) st[u] = *(const float4*)(xpt + 16 * u);
        __syncthreads();                  // previous tile fully consumed
#pragma unroll
        for (int u = 0; u < 8; u++) *(float4*)&xs[srow][sc0 + 16 * u] = st[u];
        __syncthreads();

        const float* wkt = wp + (size_t)kt * BK * NEXP;
#pragma unroll 4
        for (int k4 = 0; k4 < BK; k4 += 4) {
            const float4 xa = *(const float4*)&xs[row][k4];
            const float* xf = (const float*)&xa;
#pragma unroll
            for (int j = 0; j < 4; j++) {
                const float4* wr = (const float4*)(wkt + (size_t)(k4 + j) * NEXP);
                const float4 w0 = wr[0], w1 = wr[1], w2 = wr[2], w3 = wr[3];
                const float xv = xf[j];
                acc[0]  += xv * w0.x;  acc[1]  += xv * w0.y;
                acc[2]  += xv * w0.z;  acc[3]  += xv * w0.w;
                acc[4]  += xv * w1.x;  acc[5]  += xv * w1.y;
                acc[6]  += xv * w1.z;  acc[7]  += xv * w1.w;
                acc[8]  += xv * w2.x;  acc[9]  += xv * w2.y;
                acc[10] += xv * w2.z;  acc[11] += xv * w2.w;
                acc[12] += xv * w3.x;  acc[13] += xv * w3.y;
                acc[14] += xv * w3.z;  acc[15] += xv * w3.w;
            }
        }
    }

    float* po = part + (size_t)kh * NROWS * NEXP + (size_t)(r0 + row) * NEXP + wv * 16;
#pragma unroll
    for (int j = 0; j < 4; j++)
        *(float4*)(po + 4 * j) =
            make_float4(acc[4 * j], acc[4 * j + 1], acc[4 * j + 2], acc[4 * j + 3]);
}

// Kernel 2: one wave per row. Sum K-halves, sigmoid, +bias, top-2 (tie -> lower
// index), normalize. out layout: [weights 2N][indices-as-float 2N][scores 64N]
__global__ __launch_bounds__(256) void gate_topk_kernel(
    const float* __restrict__ part, const float* __restrict__ bias,
    float* __restrict__ out)
{
    const int tid = threadIdx.x;
    const int e   = tid & 63;
    const int row = blockIdx.x * 4 + (tid >> 6);
    const size_t idx = (size_t)row * NEXP + e;

    const float logit = part[idx] + part[(size_t)NROWS * NEXP + idx];
    const float score = 1.0f / (1.0f + expf(-logit));
    out[(size_t)4 * NROWS + idx] = score;           // scores

    const float biased = score + bias[e];

    float v = biased; int bi = e;
#pragma unroll
    for (int off = 32; off; off >>= 1) {
        const float ov = __shfl_xor(v, off);
        const int   oi = __shfl_xor(bi, off);
        if (ov > v || (ov == v && oi < bi)) { v = ov; bi = oi; }
    }
    const int i1 = bi;

    float v2 = (e == i1) ? -INFINITY : biased;
    int bi2 = e;
#pragma unroll
    for (int off = 32; off; off >>= 1) {
        const float ov = __shfl_xor(v2, off);
        const int   oi = __shfl_xor(bi2, off);
        if (ov > v2 || (ov == v2 && oi < bi2)) { v2 = ov; bi2 = oi; }
    }
    const int i2 = bi2;

    const float s1 = __shfl(score, i1);
    const float s2 = __shfl(score, i2);
    if (e == 0) {
        const float inv = 1.0f / (s1 + s2);
        out[(size_t)row * 2 + 0] = s1 * inv;
        out[(size_t)row * 2 + 1] = s2 * inv;
        out[(size_t)2 * NROWS + row * 2 + 0] = (float)i1;
        out[(size_t)2 * NROWS + row * 2 + 1] = (float)i2;
    }
}

extern "C" void kernel_launch(void* const* d_in, const int* in_sizes, int n_in,
                              void* d_out, int out_size, void* d_ws, size_t ws_size,
                              hipStream_t stream)
{
    const float* x    = (const float*)d_in[0];
    const float* w    = (const float*)d_in[1];
    const float* bias = (const float*)d_in[2];
    float* out  = (float*)d_out;
    float* part = (float*)d_ws;                                   // 4 MB
    float* wtr  = (float*)((char*)d_ws + (size_t)KSPLIT * NROWS * NEXP * 4);  // 1 MB

    transpose_w_kernel<<<DDIM / 64, 256, 0, stream>>>(w, wtr);
    dim3 g1(NROWS / BROWS, KSPLIT);
    gemm_partial_kernel<<<g1, 256, 0, stream>>>(x, wtr, part);
    gate_topk_kernel<<<NROWS / 4, 256, 0, stream>>>(part, bias, out);
}

// Round 3
// 318.064 us; speedup vs baseline: 1.3006x; 1.3006x over previous
//
#include <hip/hip_runtime.h>
#include <math.h>

#define NROWS 8192
#define DDIM  4096
#define NEXP  64
#define BROWS 128          // rows per block
#define BK    16           // k-depth per staged tile
#define XS_STRIDE 20       // 20*4B: 16B-aligned float4 rows, 2-way banks (free)
#define WS_STRIDE 68       // 68*4B: 16B-aligned, banks 4k+e (2-way, free)

// Block = 64 threads (1 wave): 16 row-groups x 4 expert-groups.
// Thread tile: 8 rows x 16 experts (acc = 128 VGPR).
// Per 4-k group per wave: 8 x-reads + 16 W-reads (b128) vs 512 FMA instrs
// -> LDS/VALU ratio ~1.125 (R1 was 3.0). Split-K for grid parallelism.
__global__ __launch_bounds__(64) void gemm_partial_kernel(
    const float* __restrict__ x, const float* __restrict__ w,
    float* __restrict__ part, int ksplit)
{
    __shared__ float xs[BROWS][XS_STRIDE];
    __shared__ float wt[BK][WS_STRIDE];

    const int l  = threadIdx.x;        // 0..63
    const int tr = l >> 2;             // 0..15 row group
    const int te = l & 3;              // 0..3 expert group (16 experts each)
    const int r0 = blockIdx.x * BROWS;
    const int kh = blockIdx.y;
    const int kchunk = DDIM / ksplit;
    const int k0 = kh * kchunk;
    const int niter = kchunk / BK;

    // staging: x tile 128x16 -> thread covers rows tr+16j, k-quad (l&3)*4
    const int skc = te * 4;
    const float* xp = x + (size_t)(r0 + tr) * DDIM + k0 + skc;
    // W staging: thread l = expert l, 16 ks (4 float4)
    const float* wp = w + (size_t)l * DDIM + k0;

    float acc[8][16];
#pragma unroll
    for (int i = 0; i < 8; i++)
#pragma unroll
        for (int j = 0; j < 16; j++) acc[i][j] = 0.f;

    float4 stx[8], stw[4];
#pragma unroll
    for (int j = 0; j < 8; j++) stx[j] = *(const float4*)(xp + (size_t)16 * j * DDIM);
#pragma unroll
    for (int u = 0; u < 4; u++) stw[u] = *(const float4*)(wp + 4 * u);

    for (int kt = 0; kt < niter; kt++) {
        __syncthreads();               // previous tile fully consumed
#pragma unroll
        for (int j = 0; j < 8; j++) *(float4*)&xs[tr + 16 * j][skc] = stx[j];
#pragma unroll
        for (int u = 0; u < 4; u++) {
            wt[4 * u + 0][l] = stw[u].x;
            wt[4 * u + 1][l] = stw[u].y;
            wt[4 * u + 2][l] = stw[u].z;
            wt[4 * u + 3][l] = stw[u].w;
        }
        __syncthreads();

        if (kt + 1 < niter) {          // prefetch next tile into regs
            const float* xpn = xp + (kt + 1) * BK;
            const float* wpn = wp + (kt + 1) * BK;
#pragma unroll
            for (int j = 0; j < 8; j++) stx[j] = *(const float4*)(xpn + (size_t)16 * j * DDIM);
#pragma unroll
            for (int u = 0; u < 4; u++) stw[u] = *(const float4*)(wpn + 4 * u);
        }

#pragma unroll
        for (int kk = 0; kk < BK; kk += 4) {
            float4 xa[8];
#pragma unroll
            for (int i = 0; i < 8; i++) xa[i] = *(const float4*)&xs[tr + 16 * i][kk];
#pragma unroll
            for (int k2 = 0; k2 < 4; k2++) {
                const float* wr = &wt[kk + k2][te * 16];
                const float4 w0 = *(const float4*)(wr + 0);
                const float4 w1 = *(const float4*)(wr + 4);
                const float4 w2 = *(const float4*)(wr + 8);
                const float4 w3 = *(const float4*)(wr + 12);
#pragma unroll
                for (int i = 0; i < 8; i++) {
                    const float xv = ((const float*)&xa[i])[k2];
                    acc[i][0]  += xv * w0.x;  acc[i][1]  += xv * w0.y;
                    acc[i][2]  += xv * w0.z;  acc[i][3]  += xv * w0.w;
                    acc[i][4]  += xv * w1.x;  acc[i][5]  += xv * w1.y;
                    acc[i][6]  += xv * w1.z;  acc[i][7]  += xv * w1.w;
                    acc[i][8]  += xv * w2.x;  acc[i][9]  += xv * w2.y;
                    acc[i][10] += xv * w2.z;  acc[i][11] += xv * w2.w;
                    acc[i][12] += xv * w3.x;  acc[i][13] += xv * w3.y;
                    acc[i][14] += xv * w3.z;  acc[i][15] += xv * w3.w;
                }
            }
        }
    }

    float* po = part + ((size_t)kh * NROWS + r0) * NEXP;
#pragma unroll
    for (int i = 0; i < 8; i++)
#pragma unroll
        for (int u = 0; u < 4; u++)
            *(float4*)&po[(size_t)(tr + 16 * i) * NEXP + te * 16 + 4 * u] =
                make_float4(acc[i][4 * u], acc[i][4 * u + 1],
                            acc[i][4 * u + 2], acc[i][4 * u + 3]);
}

// One wave per row: sum split-K partials, sigmoid, +bias, top-2 (tie -> lower
// index), normalize. out: [weights 2N][indices-as-float 2N][scores 64N]
__global__ __launch_bounds__(256) void gate_topk_kernel(
    const float* __restrict__ part, const float* __restrict__ bias,
    float* __restrict__ out, int ksplit)
{
    const int tid = threadIdx.x;
    const int e   = tid & 63;
    const int row = blockIdx.x * 4 + (tid >> 6);
    const size_t idx = (size_t)row * NEXP + e;

    float logit = 0.f;
    for (int s = 0; s < ksplit; s++)
        logit += part[(size_t)s * NROWS * NEXP + idx];
    const float score = 1.0f / (1.0f + expf(-logit));
    out[(size_t)4 * NROWS + idx] = score;           // scores

    const float biased = score + bias[e];

    float v = biased; int bi = e;
#pragma unroll
    for (int off = 32; off; off >>= 1) {
        const float ov = __shfl_xor(v, off);
        const int   oi = __shfl_xor(bi, off);
        if (ov > v || (ov == v && oi < bi)) { v = ov; bi = oi; }
    }
    const int i1 = bi;

    float v2 = (e == i1) ? -INFINITY : biased;
    int bi2 = e;
#pragma unroll
    for (int off = 32; off; off >>= 1) {
        const float ov = __shfl_xor(v2, off);
        const int   oi = __shfl_xor(bi2, off);
        if (ov > v2 || (ov == v2 && oi < bi2)) { v2 = ov; bi2 = oi; }
    }
    const int i2 = bi2;

    const float s1 = __shfl(score, i1);
    const float s2 = __shfl(score, i2);
    if (e == 0) {
        const float inv = 1.0f / (s1 + s2);
        out[(size_t)row * 2 + 0] = s1 * inv;
        out[(size_t)row * 2 + 1] = s2 * inv;
        out[(size_t)2 * NROWS + row * 2 + 0] = (float)i1;
        out[(size_t)2 * NROWS + row * 2 + 1] = (float)i2;
    }
}

extern "C" void kernel_launch(void* const* d_in, const int* in_sizes, int n_in,
                              void* d_out, int out_size, void* d_ws, size_t ws_size,
                              hipStream_t stream)
{
    const float* x    = (const float*)d_in[0];
    const float* w    = (const float*)d_in[1];
    const float* bias = (const float*)d_in[2];
    float* out  = (float*)d_out;
    float* part = (float*)d_ws;

    // split-K: 16 preferred (1024 waves = 4/CU); fall back if ws is small
    int ksplit = 16;
    while (ksplit > 1 && (size_t)ksplit * NROWS * NEXP * 4 > ws_size) ksplit >>= 1;

    dim3 g1(NROWS / BROWS, ksplit);
    gemm_partial_kernel<<<g1, 64, 0, stream>>>(x, w, part, ksplit);
    gate_topk_kernel<<<NROWS / 4, 256, 0, stream>>>(part, bias, out, ksplit);
}